// Round 2
// baseline (617.893 us; speedup 1.0000x reference)
//
#include <hip/hip_runtime.h>
#include <cstdint>

#define IN_F 4096
#define OUT_F 11008
#define NG 32
#define BM 128
#define BN 64
#define BK 64
#define NKT (IN_F / BK)   // 64 K-tiles
#define NBLK 688          // 172 strips * 4 m-blocks

typedef _Float16 half8 __attribute__((ext_vector_type(8)));
typedef _Float16 h2 __attribute__((ext_vector_type(2)));
typedef float f32x4 __attribute__((ext_vector_type(4)));

__global__ __launch_bounds__(256, 3) void qlin_mfma2(
    const float* __restrict__ x, const int* __restrict__ qw,
    const float* __restrict__ sc, const float* __restrict__ zpt,
    const float* __restrict__ bias, float* __restrict__ out)
{
    // Double-buffered, XOR-swizzled (16B-granule) LDS: 48 KB -> 3 blocks/CU
    __shared__ __align__(16) _Float16 As[2][BM * BK]; // 16 KB each
    __shared__ __align__(16) _Float16 Bs[2][BN * BK]; //  8 KB each

    const int tid = threadIdx.x;

    // --- XCD-colocation swizzle: 4 same-strip blocks => same linear id mod 8
    // panels of 32 blocks = 8 strips x 4 m-blocks; same-strip ids differ by 8.
    int L = blockIdx.x, strip, mblk;
    if (L < 672) { int p = L >> 5, i = L & 31; strip = p * 8 + (i & 7); mblk = i >> 3; }
    else         { int i = L - 672;            strip = 168 + (i & 3);   mblk = i >> 2; }
    const int m0 = mblk * BM;
    const int n0 = strip * BN;

    const int lane = tid & 63;
    const int w    = tid >> 6;        // 4 waves: 2x2 over 128x64
    const int wm   = (w & 1) * 64;
    const int wn   = (w >> 1) * 32;
    const int l16  = lane & 15;
    const int quad = lane >> 4;

    // staging map: 16B chunk c8 within row, row-group rg
    const int c8 = tid & 7;
    const int rg = tid >> 3;          // 0..31

    // prefetch registers
    float4 aP[8];                     // A: 4 rows x 8 floats (dist-1)
    int4   bq[2][2][2];               // B: 2 sets (dist-2) x 2 rows x 2 int4
    float  bsS[2][2], bzS[2][2];

    const h2 K1024 = {(_Float16)1024.0f, (_Float16)1024.0f};

    auto pfA = [&](int kt) {
        const int k0 = kt * BK;
#pragma unroll
        for (int j = 0; j < 4; ++j) {
            int row = rg + 32 * j;
            const float4* p = (const float4*)(x + (size_t)(m0 + row) * IN_F + k0 + c8 * 8);
            aP[j * 2]     = p[0];
            aP[j * 2 + 1] = p[1];
        }
    };

    auto pfB = [&](int kt, int set) {
        const int k0 = kt * BK;
        const int g  = kt >> 1;       // 128-group index
#pragma unroll
        for (int j = 0; j < 2; ++j) {
            int row = n0 + rg + 32 * j;
            const int4* p = (const int4*)(qw + (size_t)row * IN_F + k0 + c8 * 8);
            bq[set][j][0] = p[0];
            bq[set][j][1] = p[1];
            bsS[set][j] = sc [(size_t)row * NG + g];
            bzS[set][j] = zpt[(size_t)row * NG + g];
        }
    };

    auto dq2 = [&](int u0, int u1, h2 sv, h2 bv) -> uint32_t {
        uint32_t t = ((uint32_t)u0 | ((uint32_t)u1 << 16)) | 0x64006400u;
        h2 v = __builtin_bit_cast(h2, t);   // (1024+u0, 1024+u1) exact
        v = v - K1024;                      // (u0, u1) exact in f16
        v = v * sv + bv;                    // v_pk_fma_f16
        return __builtin_bit_cast(uint32_t, v);
    };

    auto stage = [&](int buf, int set) {
        // A: 4 rows x 8 f32 -> 8 f16 (16B chunk), XOR-swizzled
#pragma unroll
        for (int j = 0; j < 4; ++j) {
            int row = rg + 32 * j;
            float4 f0 = aP[j * 2], f1 = aP[j * 2 + 1];
            int4 o;
            o.x = __builtin_bit_cast(int, __builtin_amdgcn_cvt_pkrtz(f0.x, f0.y));
            o.y = __builtin_bit_cast(int, __builtin_amdgcn_cvt_pkrtz(f0.z, f0.w));
            o.z = __builtin_bit_cast(int, __builtin_amdgcn_cvt_pkrtz(f1.x, f1.y));
            o.w = __builtin_bit_cast(int, __builtin_amdgcn_cvt_pkrtz(f1.z, f1.w));
            *(int4*)&As[buf][row * BK + ((c8 ^ (row & 7)) << 3)] = o;
        }
        // B: dequant 2 rows x 8 ints via packed-f16 magic
#pragma unroll
        for (int j = 0; j < 2; ++j) {
            int row = rg + 32 * j;
            float s = bsS[set][j];
            _Float16 sh = (_Float16)s;
            _Float16 bh = (_Float16)(-bzS[set][j] * s);
            h2 sv = {sh, sh}, bv = {bh, bh};
            int4 q0 = bq[set][j][0], q1 = bq[set][j][1];
            int4 o;
            o.x = (int)dq2(q0.x, q0.y, sv, bv);
            o.y = (int)dq2(q0.z, q0.w, sv, bv);
            o.z = (int)dq2(q1.x, q1.y, sv, bv);
            o.w = (int)dq2(q1.z, q1.w, sv, bv);
            *(int4*)&Bs[buf][row * BK + ((c8 ^ (row & 7)) << 3)] = o;
        }
    };

    f32x4 acc[4][2];
#pragma unroll
    for (int mt = 0; mt < 4; ++mt)
#pragma unroll
        for (int nt = 0; nt < 2; ++nt)
            acc[mt][nt] = (f32x4){0.f, 0.f, 0.f, 0.f};

    auto compute = [&](int buf) {
#pragma unroll
        for (int ks = 0; ks < 2; ++ks) {
            half8 a[4], b[2];
            const int ck = ks * 4 + quad;   // 16B k-chunk index
#pragma unroll
            for (int mt = 0; mt < 4; ++mt) {
                int row = wm + mt * 16 + l16;
                a[mt] = *(const half8*)&As[buf][row * BK + ((ck ^ (row & 7)) << 3)];
            }
#pragma unroll
            for (int nt = 0; nt < 2; ++nt) {
                int row = wn + nt * 16 + l16;
                b[nt] = *(const half8*)&Bs[buf][row * BK + ((ck ^ (row & 7)) << 3)];
            }
#pragma unroll
            for (int mt = 0; mt < 4; ++mt)
#pragma unroll
                for (int nt = 0; nt < 2; ++nt)
                    acc[mt][nt] = __builtin_amdgcn_mfma_f32_16x16x32_f16(
                        a[mt], b[nt], acc[mt][nt], 0, 0, 0);
        }
    };

    // prologue: tile0 staged, tile1 loads in flight
    pfB(0, 0);
    pfA(0);
    stage(0, 0);
    pfB(1, 1);
    __syncthreads();

#pragma unroll 1
    for (int kt = 0; kt < NKT; ++kt) {
        const int buf = kt & 1;
        if (kt + 1 < NKT) pfA(kt + 1);          // A loads (L2-warm) for next tile
        compute(buf);                            // 32 MFMAs/wave from LDS
        if (kt + 2 < NKT) pfB(kt + 2, buf);     // B dist-2: stays in flight past barrier
        if (kt + 1 < NKT) {
            stage(buf ^ 1, (kt + 1) & 1);       // convert+dequant into other buffer
            __syncthreads();                     // single barrier per iter
        }
    }

    // epilogue: C/D layout col = lane&15, row = quad*4 + r
#pragma unroll
    for (int nt = 0; nt < 2; ++nt) {
        int n = n0 + wn + nt * 16 + l16;
        float bv = bias[n];
#pragma unroll
        for (int mt = 0; mt < 4; ++mt) {
            int mb = m0 + wm + mt * 16 + quad * 4;
#pragma unroll
            for (int r = 0; r < 4; ++r)
                out[(size_t)(mb + r) * OUT_F + n] = acc[mt][nt][r] + bv;
        }
    }
}

extern "C" void kernel_launch(void* const* d_in, const int* in_sizes, int n_in,
                              void* d_out, int out_size, void* d_ws, size_t ws_size,
                              hipStream_t stream) {
    const float* x    = (const float*)d_in[0];
    const int*   qw   = (const int*)d_in[1];
    const float* scp  = (const float*)d_in[2];
    const float* zpp  = (const float*)d_in[3];
    const float* bias = (const float*)d_in[4];
    float* out = (float*)d_out;
    (void)in_sizes; (void)n_in; (void)out_size; (void)d_ws; (void)ws_size;

    qlin_mfma2<<<dim3(NBLK), dim3(256), 0, stream>>>(x, qw, scp, zpp, bias, out);
}

// Round 3
// 467.176 us; speedup vs baseline: 1.3226x; 1.3226x over previous
//
#include <hip/hip_runtime.h>
#include <cstdint>

#define IN_F 4096
#define OUT_F 11008
#define NG 32
#define BM 128
#define BN 64
#define BK 64
#define NKT (IN_F / BK)   // 64 K-tiles
#define NBLK 688          // 172 strips * 4 m-blocks

typedef _Float16 half8 __attribute__((ext_vector_type(8)));
typedef _Float16 h2 __attribute__((ext_vector_type(2)));
typedef float f32x4 __attribute__((ext_vector_type(4)));

__global__ __launch_bounds__(256, 3) void qlin_mfma3(
    const float* __restrict__ x, const int* __restrict__ qw,
    const float* __restrict__ sc, const float* __restrict__ zpt,
    const float* __restrict__ bias, float* __restrict__ out)
{
    // Double-buffered, XOR-swizzled (16B-granule) LDS: 48 KB -> 3 blocks/CU
    __shared__ __align__(16) _Float16 As[2][BM * BK]; // 16 KB each
    __shared__ __align__(16) _Float16 Bs[2][BN * BK]; //  8 KB each

    const int tid = threadIdx.x;

    // XCD-colocation swizzle: 4 same-strip m-blocks get ids = same (mod 8)
    int L = blockIdx.x, strip, mblk;
    if (L < 672) { int p = L >> 5, i = L & 31; strip = p * 8 + (i & 7); mblk = i >> 3; }
    else         { int i = L - 672;            strip = 168 + (i & 3);   mblk = i >> 2; }
    const int m0 = mblk * BM;
    const int n0 = strip * BN;

    const int lane = tid & 63;
    const int w    = tid >> 6;        // 4 waves: 2x2 over 128x64
    const int wm   = (w & 1) * 64;
    const int wn   = (w >> 1) * 32;
    const int l16  = lane & 15;
    const int quad = lane >> 4;

    // staging map: 16B chunk c8 within row, row-group rg
    const int c8 = tid & 7;
    const int rg = tid >> 3;          // 0..31

    // prefetch registers — ONLY static indexing (dynamic idx => scratch spill!)
    float4 aP[8];                         // A: 4 rows x 8 floats (dist-1)
    int4   bqA[2][2], bqB[2][2];          // B: two named dist-2 sets
    float  bsA[2], bzA[2], bsB[2], bzB[2];

    const h2 K1024 = {(_Float16)1024.0f, (_Float16)1024.0f};

    auto pfA = [&](int kt) {
        const int k0 = kt * BK;
#pragma unroll
        for (int j = 0; j < 4; ++j) {
            int row = rg + 32 * j;
            const float4* p = (const float4*)(x + (size_t)(m0 + row) * IN_F + k0 + c8 * 8);
            aP[j * 2]     = p[0];
            aP[j * 2 + 1] = p[1];
        }
    };

    auto pfB = [&](int kt, int4 (&q)[2][2], float (&s)[2], float (&z)[2]) {
        const int k0 = kt * BK;
        const int g  = kt >> 1;       // 128-wide quant group
#pragma unroll
        for (int j = 0; j < 2; ++j) {
            int row = n0 + rg + 32 * j;
            const int4* p = (const int4*)(qw + (size_t)row * IN_F + k0 + c8 * 8);
            q[j][0] = p[0];
            q[j][1] = p[1];
            s[j] = sc [(size_t)row * NG + g];
            z[j] = zpt[(size_t)row * NG + g];
        }
    };

    auto dq2 = [&](int u0, int u1, h2 sv, h2 bv) -> int {
        uint32_t t = ((uint32_t)u0 | ((uint32_t)u1 << 16)) | 0x64006400u;
        h2 v = __builtin_bit_cast(h2, t);   // (1024+u0, 1024+u1) exact
        v = v - K1024;                      // (u0, u1) exact in f16
        v = v * sv + bv;                    // v_pk_fma_f16
        return __builtin_bit_cast(int, v);
    };

    auto stage = [&](int buf, int4 (&q)[2][2], float (&s)[2], float (&z)[2]) {
        // A: 4 rows x 8 f32 -> 8 f16 (16B chunk), XOR-swizzled
#pragma unroll
        for (int j = 0; j < 4; ++j) {
            int row = rg + 32 * j;
            float4 f0 = aP[j * 2], f1 = aP[j * 2 + 1];
            int4 o;
            o.x = __builtin_bit_cast(int, __builtin_amdgcn_cvt_pkrtz(f0.x, f0.y));
            o.y = __builtin_bit_cast(int, __builtin_amdgcn_cvt_pkrtz(f0.z, f0.w));
            o.z = __builtin_bit_cast(int, __builtin_amdgcn_cvt_pkrtz(f1.x, f1.y));
            o.w = __builtin_bit_cast(int, __builtin_amdgcn_cvt_pkrtz(f1.z, f1.w));
            *(int4*)&As[buf][row * BK + ((c8 ^ (row & 7)) << 3)] = o;
        }
        // B: dequant 2 rows x 8 ints via packed-f16 magic
#pragma unroll
        for (int j = 0; j < 2; ++j) {
            int row = rg + 32 * j;
            float sf = s[j];
            _Float16 sh = (_Float16)sf;
            _Float16 bh = (_Float16)(-z[j] * sf);
            h2 sv = {sh, sh}, bv = {bh, bh};
            int4 q0 = q[j][0], q1 = q[j][1];
            int4 o;
            o.x = dq2(q0.x, q0.y, sv, bv);
            o.y = dq2(q0.z, q0.w, sv, bv);
            o.z = dq2(q1.x, q1.y, sv, bv);
            o.w = dq2(q1.z, q1.w, sv, bv);
            *(int4*)&Bs[buf][row * BK + ((c8 ^ (row & 7)) << 3)] = o;
        }
    };

    f32x4 acc[4][2];
#pragma unroll
    for (int mt = 0; mt < 4; ++mt)
#pragma unroll
        for (int nt = 0; nt < 2; ++nt)
            acc[mt][nt] = (f32x4){0.f, 0.f, 0.f, 0.f};

    auto compute = [&](int buf) {
#pragma unroll
        for (int ks = 0; ks < 2; ++ks) {
            half8 a[4], b[2];
            const int ck = ks * 4 + quad;   // 16B k-chunk index
#pragma unroll
            for (int mt = 0; mt < 4; ++mt) {
                int row = wm + mt * 16 + l16;
                a[mt] = *(const half8*)&As[buf][row * BK + ((ck ^ (row & 7)) << 3)];
            }
#pragma unroll
            for (int nt = 0; nt < 2; ++nt) {
                int row = wn + nt * 16 + l16;
                b[nt] = *(const half8*)&Bs[buf][row * BK + ((ck ^ (row & 7)) << 3)];
            }
#pragma unroll
            for (int mt = 0; mt < 4; ++mt)
#pragma unroll
                for (int nt = 0; nt < 2; ++nt)
                    acc[mt][nt] = __builtin_amdgcn_mfma_f32_16x16x32_f16(
                        a[mt], b[nt], acc[mt][nt], 0, 0, 0);
        }
    };

    // prologue: B(0) + A(0) in flight, B(1) issued before staging tile 0
    pfB(0, bqA, bsA, bzA);
    pfA(0);
    pfB(1, bqB, bsB, bzB);
    stage(0, bqA, bsA, bzA);
    __syncthreads();

    // K-loop unrolled x2 so every buffer/set index is a compile-time constant
#pragma unroll 1
    for (int kt = 0; kt < NKT; kt += 2) {
        // even tile: compute buf0 (set A staged), stage tile kt+1 from set B
        pfA(kt + 1);
        compute(0);
        if (kt + 2 < NKT) pfB(kt + 2, bqA, bsA, bzA);
        stage(1, bqB, bsB, bzB);
        __syncthreads();
        // odd tile: compute buf1, stage tile kt+2 from set A
        if (kt + 2 < NKT) {
            pfA(kt + 2);
            compute(1);
            if (kt + 3 < NKT) pfB(kt + 3, bqB, bsB, bzB);
            stage(0, bqA, bsA, bzA);
            __syncthreads();
        } else {
            compute(1);
        }
    }

    // epilogue: C/D layout col = lane&15, row = quad*4 + r
#pragma unroll
    for (int nt = 0; nt < 2; ++nt) {
        int n = n0 + wn + nt * 16 + l16;
        float bv = bias[n];
#pragma unroll
        for (int mt = 0; mt < 4; ++mt) {
            int mb = m0 + wm + mt * 16 + quad * 4;
#pragma unroll
            for (int r = 0; r < 4; ++r)
                out[(size_t)(mb + r) * OUT_F + n] = acc[mt][nt][r] + bv;
        }
    }
}

extern "C" void kernel_launch(void* const* d_in, const int* in_sizes, int n_in,
                              void* d_out, int out_size, void* d_ws, size_t ws_size,
                              hipStream_t stream) {
    const float* x    = (const float*)d_in[0];
    const int*   qw   = (const int*)d_in[1];
    const float* scp  = (const float*)d_in[2];
    const float* zpp  = (const float*)d_in[3];
    const float* bias = (const float*)d_in[4];
    float* out = (float*)d_out;
    (void)in_sizes; (void)n_in; (void)out_size; (void)d_ws; (void)ws_size;

    qlin_mfma3<<<dim3(NBLK), dim3(256), 0, stream>>>(x, qw, scp, zpp, bias, out);
}

// Round 4
// 377.245 us; speedup vs baseline: 1.6379x; 1.2384x over previous
//
#include <hip/hip_runtime.h>
#include <cstdint>

#define IN_F 4096
#define OUT_F 11008
#define NG 32
#define BM 128
#define BN 64
#define BK 64
#define NKT (IN_F / BK)   // 64 K-tiles
#define NBLK 688          // 172 strips * 4 m-blocks

typedef _Float16 half8 __attribute__((ext_vector_type(8)));
typedef _Float16 h2 __attribute__((ext_vector_type(2)));
typedef float f32x4 __attribute__((ext_vector_type(4)));

__global__ __launch_bounds__(256, 3) void qlin_mfma4(
    const float* __restrict__ x, const int* __restrict__ qw,
    const float* __restrict__ sc, const float* __restrict__ zpt,
    const float* __restrict__ bias, float* __restrict__ out)
{
    // Double-buffered, XOR-swizzled (16B granule) LDS: 48 KB -> 3 blocks/CU
    __shared__ __align__(16) _Float16 As[2][BM * BK]; // 16 KB each
    __shared__ __align__(16) _Float16 Bs[2][BN * BK]; //  8 KB each

    const int tid = threadIdx.x;

    // XCD-colocation swizzle (proven: FETCH 936->219 MB): 4 same-strip
    // m-blocks get linear ids congruent mod 8 within a 32-block panel.
    int L = blockIdx.x, strip, mblk;
    if (L < 672) { int p = L >> 5, i = L & 31; strip = p * 8 + (i & 7); mblk = i >> 3; }
    else         { int i = L - 672;            strip = 168 + (i & 3);   mblk = i >> 2; }
    const int m0 = mblk * BM;
    const int n0 = strip * BN;

    const int lane = tid & 63;
    const int w    = tid >> 6;        // 4 waves: 2x2 over 128x64
    const int wm   = (w & 1) * 64;
    const int wn   = (w >> 1) * 32;
    const int l16  = lane & 15;
    const int quad = lane >> 4;

    // staging map: 16B granule c8 within a 64-elem row, row-group rg
    const int c8 = tid & 7;
    const int rg = tid >> 3;          // 0..31

    // Single-set dist-1 prefetch registers. IMPORTANT: arrays are indexed
    // ONLY by compile-time constants and captured by [&] (never passed as
    // lambda reference params) — round 2/3 showed that pattern defeats SROA
    // and spills one int4/iter to scratch (WRITE_SIZE 204 MB vs 22 MB).
    float4 aP[8];                     // A: 4 row-groups x 2 float4
    int4   bP[4];                     // B: 2 rows x 2 int4
    float  sP[2], zP[2];

    const h2 K1024 = {(_Float16)1024.0f, (_Float16)1024.0f};

    auto pf = [&](int kt) {
        const int k0 = kt * BK;
        const int g  = kt >> 1;       // 128-wide quant group
#pragma unroll
        for (int j = 0; j < 4; ++j) {
            int row = rg + 32 * j;
            const float4* p = (const float4*)(x + (size_t)(m0 + row) * IN_F + k0 + c8 * 8);
            aP[2 * j]     = p[0];
            aP[2 * j + 1] = p[1];
        }
#pragma unroll
        for (int j = 0; j < 2; ++j) {
            int row = n0 + rg + 32 * j;
            const int4* p = (const int4*)(qw + (size_t)row * IN_F + k0 + c8 * 8);
            bP[2 * j]     = p[0];
            bP[2 * j + 1] = p[1];
            sP[j] = sc [(size_t)row * NG + g];
            zP[j] = zpt[(size_t)row * NG + g];
        }
    };

    auto dq2 = [&](int u0, int u1, h2 sv, h2 bv) -> int {
        uint32_t t = ((uint32_t)u0 | ((uint32_t)u1 << 16)) | 0x64006400u;
        h2 v = __builtin_bit_cast(h2, t);   // (1024+u0, 1024+u1) exact
        v = v - K1024;                      // (u0, u1) exact in f16
        v = v * sv + bv;                    // v_pk_fma_f16
        return __builtin_bit_cast(int, v);
    };

    auto stage = [&](int buf) {
        // A: fp32 -> f16 packed, one 16B granule per row-group
#pragma unroll
        for (int j = 0; j < 4; ++j) {
            int row = rg + 32 * j;
            float4 f0 = aP[2 * j], f1 = aP[2 * j + 1];
            int4 o;
            o.x = __builtin_bit_cast(int, __builtin_amdgcn_cvt_pkrtz(f0.x, f0.y));
            o.y = __builtin_bit_cast(int, __builtin_amdgcn_cvt_pkrtz(f0.z, f0.w));
            o.z = __builtin_bit_cast(int, __builtin_amdgcn_cvt_pkrtz(f1.x, f1.y));
            o.w = __builtin_bit_cast(int, __builtin_amdgcn_cvt_pkrtz(f1.z, f1.w));
            *(int4*)&As[buf][row * BK + ((c8 ^ (row & 7)) << 3)] = o;
        }
        // B: dequant 2 rows x 8 ints via packed-f16 magic
#pragma unroll
        for (int j = 0; j < 2; ++j) {
            int row = rg + 32 * j;
            float sf = sP[j];
            _Float16 sh = (_Float16)sf;
            _Float16 bh = (_Float16)(-zP[j] * sf);
            h2 sv = {sh, sh}, bv = {bh, bh};
            int4 q0 = bP[2 * j], q1 = bP[2 * j + 1];
            int4 o;
            o.x = dq2(q0.x, q0.y, sv, bv);
            o.y = dq2(q0.z, q0.w, sv, bv);
            o.z = dq2(q1.x, q1.y, sv, bv);
            o.w = dq2(q1.z, q1.w, sv, bv);
            *(int4*)&Bs[buf][row * BK + ((c8 ^ (row & 7)) << 3)] = o;
        }
    };

    f32x4 acc[4][2];
#pragma unroll
    for (int mt = 0; mt < 4; ++mt)
#pragma unroll
        for (int nt = 0; nt < 2; ++nt)
            acc[mt][nt] = (f32x4){0.f, 0.f, 0.f, 0.f};

    auto compute = [&](int buf) {
#pragma unroll
        for (int ks = 0; ks < 2; ++ks) {
            half8 a[4], b[2];
            const int ck = ks * 4 + quad;   // 16B k-granule index
#pragma unroll
            for (int mt = 0; mt < 4; ++mt) {
                int row = wm + mt * 16 + l16;
                a[mt] = *(const half8*)&As[buf][row * BK + ((ck ^ (row & 7)) << 3)];
            }
#pragma unroll
            for (int nt = 0; nt < 2; ++nt) {
                int row = wn + nt * 16 + l16;
                b[nt] = *(const half8*)&Bs[buf][row * BK + ((ck ^ (row & 7)) << 3)];
            }
#pragma unroll
            for (int mt = 0; mt < 4; ++mt)
#pragma unroll
                for (int nt = 0; nt < 2; ++nt)
                    acc[mt][nt] = __builtin_amdgcn_mfma_f32_16x16x32_f16(
                        a[mt], b[nt], acc[mt][nt], 0, 0, 0);
        }
    };

    pf(0);
    stage(0);
    __syncthreads();

#pragma unroll 1
    for (int kt = 0; kt < NKT; ++kt) {
        const int buf = kt & 1;
        if (kt + 1 < NKT) {
            pf(kt + 1);               // next tile's global loads in flight
            compute(buf);             // MFMA from current buffer
            stage(buf ^ 1);           // vmcnt-wait + convert into other buffer
            __syncthreads();          // single barrier per iteration
        } else {
            compute(buf);
        }
    }

    // epilogue: C/D layout col = lane&15, row = quad*4 + r
#pragma unroll
    for (int nt = 0; nt < 2; ++nt) {
        int n = n0 + wn + nt * 16 + l16;
        float bv = bias[n];
#pragma unroll
        for (int mt = 0; mt < 4; ++mt) {
            int mb = m0 + wm + mt * 16 + quad * 4;
#pragma unroll
            for (int r = 0; r < 4; ++r)
                out[(size_t)(mb + r) * OUT_F + n] = acc[mt][nt][r] + bv;
        }
    }
}

extern "C" void kernel_launch(void* const* d_in, const int* in_sizes, int n_in,
                              void* d_out, int out_size, void* d_ws, size_t ws_size,
                              hipStream_t stream) {
    const float* x    = (const float*)d_in[0];
    const int*   qw   = (const int*)d_in[1];
    const float* scp  = (const float*)d_in[2];
    const float* zpp  = (const float*)d_in[3];
    const float* bias = (const float*)d_in[4];
    float* out = (float*)d_out;
    (void)in_sizes; (void)n_in; (void)out_size; (void)d_ws; (void)ws_size;

    qlin_mfma4<<<dim3(NBLK), dim3(256), 0, stream>>>(x, qw, scp, zpp, bias, out);
}

// Round 6
// 349.592 us; speedup vs baseline: 1.7675x; 1.0791x over previous
//
#include <hip/hip_runtime.h>
#include <cstdint>

#define IN_F 4096
#define OUT_F 11008
#define NG 32
#define BM 128
#define BN 64
#define BK 64
#define NKT 64
#define NBLK 688

typedef _Float16 half8 __attribute__((ext_vector_type(8)));
typedef _Float16 h2 __attribute__((ext_vector_type(2)));
typedef float f32x4 __attribute__((ext_vector_type(4)));

__device__ __forceinline__ int dq2(int u0, int u1, h2 sv, h2 bv) {
    // (q | 0x6400) as f16 = 1024+q exactly (q in [0,16)); subtract, then fma
    uint32_t t = ((uint32_t)u0 | ((uint32_t)u1 << 16)) | 0x64006400u;
    h2 v = __builtin_bit_cast(h2, t);
    v = v - (h2){(_Float16)1024.0f, (_Float16)1024.0f};
    v = v * sv + bv;
    return __builtin_bit_cast(int, v);
}

// ---------- prepass: x fp32 -> f16 into d_ws (512*4096 elems, 8/thread) ----
__global__ __launch_bounds__(256) void cvt_x(const float* __restrict__ x,
                                             _Float16* __restrict__ xh) {
    int i = (blockIdx.x * 256 + threadIdx.x) * 8;
    float4 f0 = *(const float4*)(x + i);
    float4 f1 = *(const float4*)(x + i + 4);
    int4 o;
    o.x = __builtin_bit_cast(int, __builtin_amdgcn_cvt_pkrtz(f0.x, f0.y));
    o.y = __builtin_bit_cast(int, __builtin_amdgcn_cvt_pkrtz(f0.z, f0.w));
    o.z = __builtin_bit_cast(int, __builtin_amdgcn_cvt_pkrtz(f1.x, f1.y));
    o.w = __builtin_bit_cast(int, __builtin_amdgcn_cvt_pkrtz(f1.z, f1.w));
    *(int4*)(xh + i) = o;
}

// ---------- main GEMM: A from f16 xh, dist-2 B prefetch, stage-first -------
// Macros (not lambdas with array refs!) keep every register name static —
// rounds 2/3 showed dynamic indexing / ref-params spill 16 B/thread/iter.
// NOTE: pasted identifiers are parenthesized — `q##S##0.x` would tokenize
// `0.x` as one pp-number and break the paste.

#define PF_A(kt) do {                                                          \
    const _Float16* _p = xh + (size_t)(m0 + rg) * IN_F + (kt) * BK + c8 * 8;   \
    aP0 = *(const int4*)(_p);                                                  \
    aP1 = *(const int4*)(_p + (size_t)32 * IN_F);                              \
    aP2 = *(const int4*)(_p + (size_t)64 * IN_F);                              \
    aP3 = *(const int4*)(_p + (size_t)96 * IN_F);                              \
} while (0)

#define PF_B(kt, S) do {                                                       \
    const int _k0 = (kt) * BK; const int _g = (kt) >> 1;                       \
    const int* _p0 = qw + (size_t)(n0 + rg) * IN_F + _k0 + c8 * 8;             \
    (q##S##0) = *(const int4*)(_p0);                                           \
    (q##S##1) = *(const int4*)(_p0 + 4);                                       \
    (q##S##2) = *(const int4*)(_p0 + (size_t)32 * IN_F);                       \
    (q##S##3) = *(const int4*)(_p0 + (size_t)32 * IN_F + 4);                   \
    (s##S##0) = sc [(size_t)(n0 + rg) * NG + _g];                              \
    (s##S##1) = sc [(size_t)(n0 + rg + 32) * NG + _g];                         \
    (z##S##0) = zpt[(size_t)(n0 + rg) * NG + _g];                              \
    (z##S##1) = zpt[(size_t)(n0 + rg + 32) * NG + _g];                         \
} while (0)

#define STAGE_A(buf) do {                                                      \
    *(int4*)&As[buf][(rg)      * BK + xo] = aP0;                               \
    *(int4*)&As[buf][(rg + 32) * BK + xo] = aP1;                               \
    *(int4*)&As[buf][(rg + 64) * BK + xo] = aP2;                               \
    *(int4*)&As[buf][(rg + 96) * BK + xo] = aP3;                               \
} while (0)

#define STAGE_B(buf, S) do {                                                   \
    float _s0 = (s##S##0); _Float16 _h0 = (_Float16)_s0;                       \
    _Float16 _b0 = (_Float16)(-(z##S##0) * _s0);                               \
    h2 _sv0 = {_h0, _h0}, _bv0 = {_b0, _b0};                                   \
    int4 _o;                                                                   \
    _o.x = dq2((q##S##0).x, (q##S##0).y, _sv0, _bv0);                          \
    _o.y = dq2((q##S##0).z, (q##S##0).w, _sv0, _bv0);                          \
    _o.z = dq2((q##S##1).x, (q##S##1).y, _sv0, _bv0);                          \
    _o.w = dq2((q##S##1).z, (q##S##1).w, _sv0, _bv0);                          \
    *(int4*)&Bs[buf][(rg) * BK + xo] = _o;                                     \
    float _s1 = (s##S##1); _Float16 _h1 = (_Float16)_s1;                       \
    _Float16 _b1 = (_Float16)(-(z##S##1) * _s1);                               \
    h2 _sv1 = {_h1, _h1}, _bv1 = {_b1, _b1};                                   \
    _o.x = dq2((q##S##2).x, (q##S##2).y, _sv1, _bv1);                          \
    _o.y = dq2((q##S##2).z, (q##S##2).w, _sv1, _bv1);                          \
    _o.z = dq2((q##S##3).x, (q##S##3).y, _sv1, _bv1);                          \
    _o.w = dq2((q##S##3).z, (q##S##3).w, _sv1, _bv1);                          \
    *(int4*)&Bs[buf][(rg + 32) * BK + xo] = _o;                                \
} while (0)

__global__ __launch_bounds__(256, 3) void qlin_mfma5(
    const _Float16* __restrict__ xh, const int* __restrict__ qw,
    const float* __restrict__ sc, const float* __restrict__ zpt,
    const float* __restrict__ bias, float* __restrict__ out)
{
    __shared__ __align__(16) _Float16 As[2][BM * BK]; // 16 KB each
    __shared__ __align__(16) _Float16 Bs[2][BN * BK]; //  8 KB each

    const int tid = threadIdx.x;
    // XCD-colocation swizzle (proven: FETCH 936->219->175 MB)
    int L = blockIdx.x, strip, mblk;
    if (L < 672) { int p = L >> 5, i = L & 31; strip = p * 8 + (i & 7); mblk = i >> 3; }
    else         { int i = L - 672;            strip = 168 + (i & 3);   mblk = i >> 2; }
    const int m0 = mblk * BM;
    const int n0 = strip * BN;

    const int lane = tid & 63;
    const int w    = tid >> 6;
    const int wm   = (w & 1) * 64;
    const int wn   = (w >> 1) * 32;
    const int l16  = lane & 15;
    const int quad = lane >> 4;

    const int c8 = tid & 7;               // 16B granule within 64-elem row
    const int rg = tid >> 3;              // 0..31
    const int xo = (c8 ^ (rg & 7)) << 3;  // XOR-swizzled slot

    int4 aP0, aP1, aP2, aP3;                           // A f16 prefetch (dist-1)
    int4 qA0, qA1, qA2, qA3; float sA0, sA1, zA0, zA1; // B set A (dist-2)
    int4 qB0, qB1, qB2, qB3; float sB0, sB1, zB0, zB1; // B set B (dist-2)

    f32x4 acc[4][2];
#pragma unroll
    for (int mt = 0; mt < 4; ++mt)
#pragma unroll
        for (int nt = 0; nt < 2; ++nt)
            acc[mt][nt] = (f32x4){0.f, 0.f, 0.f, 0.f};

    auto compute = [&](int buf) {
#pragma unroll
        for (int ks = 0; ks < 2; ++ks) {
            half8 a[4], b[2];
            const int ck = ks * 4 + quad;
#pragma unroll
            for (int mt = 0; mt < 4; ++mt) {
                int row = wm + mt * 16 + l16;
                a[mt] = *(const half8*)&As[buf][row * BK + ((ck ^ (row & 7)) << 3)];
            }
#pragma unroll
            for (int nt = 0; nt < 2; ++nt) {
                int row = wn + nt * 16 + l16;
                b[nt] = *(const half8*)&Bs[buf][row * BK + ((ck ^ (row & 7)) << 3)];
            }
#pragma unroll
            for (int mt = 0; mt < 4; ++mt)
#pragma unroll
                for (int nt = 0; nt < 2; ++nt)
                    acc[mt][nt] = __builtin_amdgcn_mfma_f32_16x16x32_f16(
                        a[mt], b[nt], acc[mt][nt], 0, 0, 0);
        }
    };

    // prologue: tile0 staged into buf0; setB holds tile1; setA refilled to tile2
    PF_B(0, A);
    PF_A(0);
    PF_B(1, B);
    STAGE_A(0);
    STAGE_B(0, A);
    PF_A(1);
    PF_B(2, A);
    __syncthreads();

#pragma unroll 1
    for (int kt = 0; kt < NKT; kt += 2) {
        // even tile: stage kt+1 (aP, setB) into buf1 FIRST (vmcnt wait at iter
        // start -> dist-2 coverage), then compute buf0
        {
            STAGE_A(1);
            STAGE_B(1, B);
            int ka = kt + 2 < NKT ? kt + 2 : NKT - 1;
            int kb = kt + 3 < NKT ? kt + 3 : NKT - 1;
            PF_A(ka);
            PF_B(kb, B);
        }
        compute(0);
        __syncthreads();
        // odd tile: stage kt+2 (aP, setA) into buf0, compute buf1
        if (kt + 2 < NKT) {
            STAGE_A(0);
            STAGE_B(0, A);
            int ka = kt + 3 < NKT ? kt + 3 : NKT - 1;
            int kb = kt + 4 < NKT ? kt + 4 : NKT - 1;
            PF_A(ka);
            PF_B(kb, A);
        }
        compute(1);
        __syncthreads();
    }

    // epilogue: C/D layout col = lane&15, row = quad*4 + r
#pragma unroll
    for (int nt = 0; nt < 2; ++nt) {
        int n = n0 + wn + nt * 16 + l16;
        float bv = bias[n];
#pragma unroll
        for (int mt = 0; mt < 4; ++mt) {
            int mb = m0 + wm + mt * 16 + quad * 4;
#pragma unroll
            for (int r = 0; r < 4; ++r)
                out[(size_t)(mb + r) * OUT_F + n] = acc[mt][nt][r] + bv;
        }
    }
}

// ---------- fallback (proven round-4 kernel): fp32 x, dist-1 ---------------
__global__ __launch_bounds__(256, 3) void qlin_mfma4(
    const float* __restrict__ x, const int* __restrict__ qw,
    const float* __restrict__ sc, const float* __restrict__ zpt,
    const float* __restrict__ bias, float* __restrict__ out)
{
    __shared__ __align__(16) _Float16 As[2][BM * BK];
    __shared__ __align__(16) _Float16 Bs[2][BN * BK];

    const int tid = threadIdx.x;
    int L = blockIdx.x, strip, mblk;
    if (L < 672) { int p = L >> 5, i = L & 31; strip = p * 8 + (i & 7); mblk = i >> 3; }
    else         { int i = L - 672;            strip = 168 + (i & 3);   mblk = i >> 2; }
    const int m0 = mblk * BM;
    const int n0 = strip * BN;

    const int lane = tid & 63;
    const int w    = tid >> 6;
    const int wm   = (w & 1) * 64;
    const int wn   = (w >> 1) * 32;
    const int l16  = lane & 15;
    const int quad = lane >> 4;

    const int c8 = tid & 7;
    const int rg = tid >> 3;

    float4 aP[8];
    int4   bP[4];
    float  sP[2], zP[2];

    auto pf = [&](int kt) {
        const int k0 = kt * BK;
        const int g  = kt >> 1;
#pragma unroll
        for (int j = 0; j < 4; ++j) {
            int row = rg + 32 * j;
            const float4* p = (const float4*)(x + (size_t)(m0 + row) * IN_F + k0 + c8 * 8);
            aP[2 * j]     = p[0];
            aP[2 * j + 1] = p[1];
        }
#pragma unroll
        for (int j = 0; j < 2; ++j) {
            int row = n0 + rg + 32 * j;
            const int4* p = (const int4*)(qw + (size_t)row * IN_F + k0 + c8 * 8);
            bP[2 * j]     = p[0];
            bP[2 * j + 1] = p[1];
            sP[j] = sc [(size_t)row * NG + g];
            zP[j] = zpt[(size_t)row * NG + g];
        }
    };

    auto stage = [&](int buf) {
#pragma unroll
        for (int j = 0; j < 4; ++j) {
            int row = rg + 32 * j;
            float4 f0 = aP[2 * j], f1 = aP[2 * j + 1];
            int4 o;
            o.x = __builtin_bit_cast(int, __builtin_amdgcn_cvt_pkrtz(f0.x, f0.y));
            o.y = __builtin_bit_cast(int, __builtin_amdgcn_cvt_pkrtz(f0.z, f0.w));
            o.z = __builtin_bit_cast(int, __builtin_amdgcn_cvt_pkrtz(f1.x, f1.y));
            o.w = __builtin_bit_cast(int, __builtin_amdgcn_cvt_pkrtz(f1.z, f1.w));
            *(int4*)&As[buf][row * BK + ((c8 ^ (row & 7)) << 3)] = o;
        }
#pragma unroll
        for (int j = 0; j < 2; ++j) {
            int row = rg + 32 * j;
            float sf = sP[j];
            _Float16 sh = (_Float16)sf;
            _Float16 bh = (_Float16)(-zP[j] * sf);
            h2 sv = {sh, sh}, bv = {bh, bh};
            int4 q0 = bP[2 * j], q1 = bP[2 * j + 1];
            int4 o;
            o.x = dq2(q0.x, q0.y, sv, bv);
            o.y = dq2(q0.z, q0.w, sv, bv);
            o.z = dq2(q1.x, q1.y, sv, bv);
            o.w = dq2(q1.z, q1.w, sv, bv);
            *(int4*)&Bs[buf][row * BK + ((c8 ^ (row & 7)) << 3)] = o;
        }
    };

    f32x4 acc[4][2];
#pragma unroll
    for (int mt = 0; mt < 4; ++mt)
#pragma unroll
        for (int nt = 0; nt < 2; ++nt)
            acc[mt][nt] = (f32x4){0.f, 0.f, 0.f, 0.f};

    auto compute = [&](int buf) {
#pragma unroll
        for (int ks = 0; ks < 2; ++ks) {
            half8 a[4], b[2];
            const int ck = ks * 4 + quad;
#pragma unroll
            for (int mt = 0; mt < 4; ++mt) {
                int row = wm + mt * 16 + l16;
                a[mt] = *(const half8*)&As[buf][row * BK + ((ck ^ (row & 7)) << 3)];
            }
#pragma unroll
            for (int nt = 0; nt < 2; ++nt) {
                int row = wn + nt * 16 + l16;
                b[nt] = *(const half8*)&Bs[buf][row * BK + ((ck ^ (row & 7)) << 3)];
            }
#pragma unroll
            for (int mt = 0; mt < 4; ++mt)
#pragma unroll
                for (int nt = 0; nt < 2; ++nt)
                    acc[mt][nt] = __builtin_amdgcn_mfma_f32_16x16x32_f16(
                        a[mt], b[nt], acc[mt][nt], 0, 0, 0);
        }
    };

    pf(0);
    stage(0);
    __syncthreads();

#pragma unroll 1
    for (int kt = 0; kt < NKT; ++kt) {
        const int buf = kt & 1;
        if (kt + 1 < NKT) {
            pf(kt + 1);
            compute(buf);
            stage(buf ^ 1);
            __syncthreads();
        } else {
            compute(buf);
        }
    }

#pragma unroll
    for (int nt = 0; nt < 2; ++nt) {
        int n = n0 + wn + nt * 16 + l16;
        float bv = bias[n];
#pragma unroll
        for (int mt = 0; mt < 4; ++mt) {
            int mb = m0 + wm + mt * 16 + quad * 4;
#pragma unroll
            for (int r = 0; r < 4; ++r)
                out[(size_t)(mb + r) * OUT_F + n] = acc[mt][nt][r] + bv;
        }
    }
}

extern "C" void kernel_launch(void* const* d_in, const int* in_sizes, int n_in,
                              void* d_out, int out_size, void* d_ws, size_t ws_size,
                              hipStream_t stream) {
    const float* x    = (const float*)d_in[0];
    const int*   qw   = (const int*)d_in[1];
    const float* scp  = (const float*)d_in[2];
    const float* zpp  = (const float*)d_in[3];
    const float* bias = (const float*)d_in[4];
    float* out = (float*)d_out;
    (void)in_sizes; (void)n_in; (void)out_size;

    const size_t need = (size_t)512 * IN_F * sizeof(_Float16); // 4 MB
    if (ws_size >= need) {
        _Float16* xh = (_Float16*)d_ws;
        cvt_x<<<dim3(1024), dim3(256), 0, stream>>>(x, xh);
        qlin_mfma5<<<dim3(NBLK), dim3(256), 0, stream>>>(xh, qw, scp, zpp, bias, out);
    } else {
        qlin_mfma4<<<dim3(NBLK), dim3(256), 0, stream>>>(x, qw, scp, zpp, bias, out);
    }
}